// Round 1
// baseline (1135.097 us; speedup 1.0000x reference)
//
#include <hip/hip_runtime.h>
#include <hip/hip_bf16.h>
#include <math.h>

#define DEVFN __device__ __forceinline__

typedef unsigned int uint32;
typedef unsigned short ushort_t;

using bf16x8 = __attribute__((ext_vector_type(8))) short;
using f32x4  = __attribute__((ext_vector_type(4))) float;

DEVFN float bf2f(ushort_t u) {
    union { uint32 i; float f; } v; v.i = ((uint32)u) << 16; return v.f;
}
DEVFN ushort_t f2bf(float f) {
    union { float f; uint32 i; } v; v.f = f;
    uint32 u = v.i;
    uint32 r = (u + 0x7FFFu + ((u >> 16) & 1u)) >> 16;
    return (ushort_t)r;
}

DEVFN void gload_lds16(const void* g, void* l) {
    __builtin_amdgcn_global_load_lds(
        (const __attribute__((address_space(1))) void*)g,
        (__attribute__((address_space(3))) void*)l, 16, 0, 0);
}

// ---------- casts ----------
__global__ void k_cast_x(const float* __restrict__ x, ushort_t* __restrict__ xb, int N) {
    int total = N * 128;
    for (int i = blockIdx.x * blockDim.x + threadIdx.x; i < total; i += gridDim.x * blockDim.x) {
        int col = i & 127, row = i >> 7;
        float v = (col < 100) ? x[row * 100 + col] : 0.f;
        xb[i] = f2bf(v);
    }
}

// w: [K][Nout] row-major f32 -> wt: [Np][Kp] bf16 (transposed + zero-padded)
__global__ void k_cast_w(const float* __restrict__ w, ushort_t* __restrict__ wt,
                         int K, int Nout, int Kp, int Np) {
    int total = Np * Kp;
    for (int i = blockIdx.x * blockDim.x + threadIdx.x; i < total; i += gridDim.x * blockDim.x) {
        int k = i % Kp, n = i / Kp;
        float v = (k < K && n < Nout) ? w[k * Nout + n] : 0.f;
        wt[i] = f2bf(v);
    }
}

// ---------- CSR build ----------
__global__ void k_hist(const int* __restrict__ dst, int E, int* __restrict__ deg) {
    for (int i = blockIdx.x * blockDim.x + threadIdx.x; i < E; i += gridDim.x * blockDim.x)
        atomicAdd(&deg[dst[i]], 1);
}

__global__ void k_blocksum(const int* __restrict__ deg, int N, int* __restrict__ bsum) {
    __shared__ int s[1024];
    int i = blockIdx.x * 1024 + threadIdx.x;
    s[threadIdx.x] = (i < N) ? deg[i] : 0;
    __syncthreads();
    for (int o = 512; o > 0; o >>= 1) {
        if (threadIdx.x < o) s[threadIdx.x] += s[threadIdx.x + o];
        __syncthreads();
    }
    if (threadIdx.x == 0) bsum[blockIdx.x] = s[0];
}

__global__ void k_scanb(int* __restrict__ bsum, int NB) {
    if (blockIdx.x == 0 && threadIdx.x == 0) {
        int acc = 0;
        for (int i = 0; i < NB; ++i) { int v = bsum[i]; bsum[i] = acc; acc += v; }
    }
}

__global__ void k_offsets(const int* __restrict__ deg, const int* __restrict__ bsum,
                          int N, int* __restrict__ offs, int* __restrict__ cur) {
    __shared__ int s[1024];
    int t = threadIdx.x;
    int i = blockIdx.x * 1024 + t;
    int v = (i < N) ? deg[i] : 0;
    s[t] = v;
    __syncthreads();
    for (int o = 1; o < 1024; o <<= 1) {
        int add = (t >= o) ? s[t - o] : 0;
        __syncthreads();
        s[t] += add;
        __syncthreads();
    }
    int ex = s[t] - v + bsum[blockIdx.x];
    if (i < N) { offs[i] = ex; cur[i] = ex; }
}

__global__ void k_fill(const int* __restrict__ src, const int* __restrict__ dst, int E,
                       int* __restrict__ cur, int* __restrict__ csr) {
    for (int i = blockIdx.x * blockDim.x + threadIdx.x; i < E; i += gridDim.x * blockDim.x) {
        int d = dst[i];
        int slot = atomicAdd(&cur[d], 1);
        csr[slot] = src[i];
    }
}

// ---------- aggregation: one wave per node, mean of neighbor features ----------
template <int DIMS>
__global__ void k_agg(const ushort_t* __restrict__ h, const int* __restrict__ offs,
                      const int* __restrict__ deg, const int* __restrict__ csr,
                      int N, ushort_t* __restrict__ mean) {
    constexpr int VPL = DIMS / 64;  // bf16 per lane
    int wid = (blockIdx.x * blockDim.x + threadIdx.x) >> 6;
    int lane = threadIdx.x & 63;
    if (wid >= N) return;
    int off = offs[wid], cnt = deg[wid];
    float acc[VPL];
#pragma unroll
    for (int v = 0; v < VPL; ++v) acc[v] = 0.f;
    const ushort_t* hp = h + lane * VPL;
    for (int j = 0; j < cnt; ++j) {
        int s = csr[off + j];
        if constexpr (VPL == 2) {
            uint32 u = *(const uint32*)(hp + (size_t)s * DIMS);
            acc[0] += bf2f((ushort_t)(u & 0xffff));
            acc[1] += bf2f((ushort_t)(u >> 16));
        } else {
            uint2 u = *(const uint2*)(hp + (size_t)s * DIMS);
            acc[0] += bf2f((ushort_t)(u.x & 0xffff));
            acc[1] += bf2f((ushort_t)(u.x >> 16));
            acc[2] += bf2f((ushort_t)(u.y & 0xffff));
            acc[3] += bf2f((ushort_t)(u.y >> 16));
        }
    }
    float inv = 1.f / fmaxf((float)cnt, 1.f);
    if constexpr (VPL == 2) {
        uint32 o = (uint32)f2bf(acc[0] * inv) | ((uint32)f2bf(acc[1] * inv) << 16);
        *(uint32*)(mean + (size_t)wid * DIMS + lane * 2) = o;
    } else {
        uint2 o;
        o.x = (uint32)f2bf(acc[0] * inv) | ((uint32)f2bf(acc[1] * inv) << 16);
        o.y = (uint32)f2bf(acc[2] * inv) | ((uint32)f2bf(acc[3] * inv) << 16);
        *(uint2*)(mean + (size_t)wid * DIMS + lane * 4) = o;
    }
}

// ---------- dual-A MFMA GEMM: out = A1@B1^T + A2@B2^T + bias ----------
// A: [M][KP] bf16 row-major.  B: [BNtot][KP] bf16 (pre-transposed weights).
template <int BN, int WAVES_N, int WM, int WN>
__global__ __launch_bounds__(256) void k_gemm(
    const ushort_t* __restrict__ A1, const ushort_t* __restrict__ B1,
    const ushort_t* __restrict__ A2, const ushort_t* __restrict__ B2,
    int KP, const float* __restrict__ bias, int nbias,
    float* __restrict__ out, int M, int ostride) {
    constexpr int BM = 128, BK = 32;
    constexpr int M_REP = WM / 16, N_REP = WN / 16;
    __shared__ ushort_t Alds[BM * BK];
    __shared__ ushort_t Blds[BN * BK];
    const int tid = threadIdx.x, lane = tid & 63, wid = tid >> 6;
    const int wm = wid / WAVES_N, wn = wid % WAVES_N;
    const int row0 = blockIdx.x * BM, col0 = blockIdx.y * BN;
    f32x4 acc[M_REP][N_REP] = {};
    for (int side = 0; side < 2; ++side) {
        const ushort_t* A = side ? A2 : A1;
        const ushort_t* B = side ? B2 : B1;
        for (int kt = 0; kt < KP; kt += BK) {
            __syncthreads();  // protect LDS from prior iteration's readers
            for (int i = tid; i < BM * 4; i += 256) {
                int r = i >> 2, c = i & 3;
                int gr = row0 + r;
                if (gr >= M) gr = M - 1;
                gload_lds16(A + (size_t)gr * KP + kt + c * 8, Alds + i * 8);
            }
            for (int i = tid; i < BN * 4; i += 256) {
                int r = i >> 2, c = i & 3;
                gload_lds16(B + (size_t)(col0 + r) * KP + kt + c * 8, Blds + i * 8);
            }
            __syncthreads();
            bf16x8 a[M_REP], b[N_REP];
#pragma unroll
            for (int m = 0; m < M_REP; ++m)
                a[m] = *(const bf16x8*)&Alds[(wm * WM + m * 16 + (lane & 15)) * BK + (lane >> 4) * 8];
#pragma unroll
            for (int n = 0; n < N_REP; ++n)
                b[n] = *(const bf16x8*)&Blds[(wn * WN + n * 16 + (lane & 15)) * BK + (lane >> 4) * 8];
#pragma unroll
            for (int m = 0; m < M_REP; ++m)
#pragma unroll
                for (int n = 0; n < N_REP; ++n)
                    acc[m][n] = __builtin_amdgcn_mfma_f32_16x16x32_bf16(a[m], b[n], acc[m][n], 0, 0, 0);
        }
    }
#pragma unroll
    for (int m = 0; m < M_REP; ++m) {
#pragma unroll
        for (int n = 0; n < N_REP; ++n) {
            int col = col0 + wn * WN + n * 16 + (lane & 15);
            float bv = (col < nbias) ? bias[col] : 0.f;
#pragma unroll
            for (int r = 0; r < 4; ++r) {
                int row = row0 + wm * WM + m * 16 + (lane >> 4) * 4 + r;
                if (row < M) out[(size_t)row * ostride + col] = acc[m][n][r] + bv;
            }
        }
    }
}

// ---------- BN stats: column sums / sumsq over [M][256] ----------
__global__ void k_stats(const float* __restrict__ h, int M, float* __restrict__ stats) {
    int c = threadIdx.x;  // 256 threads = 256 cols
    float s = 0.f, sq = 0.f;
    for (int r = blockIdx.x; r < M; r += gridDim.x) {
        float v = h[(size_t)r * 256 + c];
        s += v;
        sq += v * v;
    }
    atomicAdd(&stats[c], s);
    atomicAdd(&stats[256 + c], sq);
}

__global__ void k_bnrelu(const float* __restrict__ h, const float* __restrict__ stats,
                         const float* __restrict__ g, const float* __restrict__ be,
                         int M, ushort_t* __restrict__ out) {
    int c = threadIdx.x;
    float mean = stats[c] / (float)M;
    float var = stats[256 + c] / (float)M - mean * mean;
    float sc = g[c] * rsqrtf(var + 1e-5f);
    float sh = be[c] - mean * sc;
    for (int r = blockIdx.x; r < M; r += gridDim.x) {
        float v = h[(size_t)r * 256 + c] * sc + sh;
        out[(size_t)r * 256 + c] = f2bf(fmaxf(v, 0.f));
    }
}

// ---------- log_softmax over 47 classes (logits padded to stride 64) ----------
__global__ void k_lsm(const float* __restrict__ logits, int M, float* __restrict__ out) {
    int w = (blockIdx.x * blockDim.x + threadIdx.x) >> 6;
    int lane = threadIdx.x & 63;
    if (w >= M) return;
    float v = (lane < 47) ? logits[(size_t)w * 64 + lane] : -1e30f;
    float m = v;
    for (int o = 32; o > 0; o >>= 1) m = fmaxf(m, __shfl_xor(m, o));
    float e = (lane < 47) ? expf(v - m) : 0.f;
    float s = e;
    for (int o = 32; o > 0; o >>= 1) s += __shfl_xor(s, o);
    if (lane < 47) out[(size_t)w * 47 + lane] = v - m - logf(s);
}

extern "C" void kernel_launch(void* const* d_in, const int* in_sizes, int n_in,
                              void* d_out, int out_size, void* d_ws, size_t ws_size,
                              hipStream_t stream) {
    const float* x   = (const float*)d_in[0];
    const int*   ei  = (const int*)d_in[1];
    const float* wl0 = (const float*)d_in[2];
    const float* wr0 = (const float*)d_in[3];
    const float* b0  = (const float*)d_in[4];
    const float* g0  = (const float*)d_in[5];
    const float* be0 = (const float*)d_in[6];
    const float* wl1 = (const float*)d_in[7];
    const float* wr1 = (const float*)d_in[8];
    const float* b1  = (const float*)d_in[9];
    const float* g1  = (const float*)d_in[10];
    const float* be1 = (const float*)d_in[11];
    const float* wl2 = (const float*)d_in[12];
    const float* wr2 = (const float*)d_in[13];
    const float* b2  = (const float*)d_in[14];
    float* out = (float*)d_out;

    const int N = in_sizes[0] / 100;
    const int E = in_sizes[1] / 2;
    const int* src = ei;
    const int* dst = ei + E;

    // workspace carve (256B aligned)
    char* p = (char*)d_ws;
    auto alloc = [&](size_t bytes) -> char* {
        char* r = p;
        p += (bytes + 255) & ~(size_t)255;
        return r;
    };
    ushort_t* xb   = (ushort_t*)alloc((size_t)N * 128 * 2);
    ushort_t* hbuf = (ushort_t*)alloc((size_t)N * 256 * 2);
    ushort_t* mean = (ushort_t*)alloc((size_t)N * 256 * 2);
    float*    hpre = (float*)alloc((size_t)N * 256 * 4);
    int* deg  = (int*)alloc((size_t)N * 4);
    int* offs = (int*)alloc((size_t)N * 4);
    int* cur  = (int*)alloc((size_t)N * 4);
    int* csr  = (int*)alloc((size_t)E * 4);
    int* bsum = (int*)alloc(1024 * 4);
    float* stats = (float*)alloc(512 * 4);
    ushort_t* wlt0 = (ushort_t*)alloc(256 * 128 * 2);
    ushort_t* wrt0 = (ushort_t*)alloc(256 * 128 * 2);
    ushort_t* wlt1 = (ushort_t*)alloc(256 * 256 * 2);
    ushort_t* wrt1 = (ushort_t*)alloc(256 * 256 * 2);
    ushort_t* wlt2 = (ushort_t*)alloc(64 * 256 * 2);
    ushort_t* wrt2 = (ushort_t*)alloc(64 * 256 * 2);
    if ((size_t)(p - (char*)d_ws) > ws_size) return;  // insufficient scratch

    hipMemsetAsync(deg, 0, (size_t)N * 4, stream);

    k_cast_x<<<2048, 256, 0, stream>>>(x, xb, N);
    k_cast_w<<<128, 256, 0, stream>>>(wl0, wlt0, 100, 256, 128, 256);
    k_cast_w<<<128, 256, 0, stream>>>(wr0, wrt0, 100, 256, 128, 256);
    k_cast_w<<<128, 256, 0, stream>>>(wl1, wlt1, 256, 256, 256, 256);
    k_cast_w<<<128, 256, 0, stream>>>(wr1, wrt1, 256, 256, 256, 256);
    k_cast_w<<<128, 256, 0, stream>>>(wl2, wlt2, 256, 47, 256, 64);
    k_cast_w<<<128, 256, 0, stream>>>(wr2, wrt2, 256, 47, 256, 64);

    k_hist<<<2048, 256, 0, stream>>>(dst, E, deg);
    int NB = (N + 1023) / 1024;
    k_blocksum<<<NB, 1024, 0, stream>>>(deg, N, bsum);
    k_scanb<<<1, 64, 0, stream>>>(bsum, NB);
    k_offsets<<<NB, 1024, 0, stream>>>(deg, bsum, N, offs, cur);
    k_fill<<<2048, 256, 0, stream>>>(src, dst, E, cur, csr);

    int aggBlocks = (N + 3) / 4;      // 4 waves (nodes) per 256-thread block
    int gemmM = (N + 127) / 128;

    // ---- layer 0 ----
    k_agg<128><<<aggBlocks, 256, 0, stream>>>(xb, offs, deg, csr, N, mean);
    k_gemm<128, 2, 64, 64><<<dim3(gemmM, 2), 256, 0, stream>>>(
        mean, wlt0, xb, wrt0, 128, b0, 256, hpre, N, 256);
    hipMemsetAsync(stats, 0, 512 * 4, stream);
    k_stats<<<256, 256, 0, stream>>>(hpre, N, stats);
    k_bnrelu<<<2048, 256, 0, stream>>>(hpre, stats, g0, be0, N, hbuf);

    // ---- layer 1 ----
    k_agg<256><<<aggBlocks, 256, 0, stream>>>(hbuf, offs, deg, csr, N, mean);
    k_gemm<128, 2, 64, 64><<<dim3(gemmM, 2), 256, 0, stream>>>(
        mean, wlt1, hbuf, wrt1, 256, b1, 256, hpre, N, 256);
    hipMemsetAsync(stats, 0, 512 * 4, stream);
    k_stats<<<256, 256, 0, stream>>>(hpre, N, stats);
    k_bnrelu<<<2048, 256, 0, stream>>>(hpre, stats, g1, be1, N, hbuf);

    // ---- layer 2 ----
    k_agg<256><<<aggBlocks, 256, 0, stream>>>(hbuf, offs, deg, csr, N, mean);
    float* logits = hpre;  // reuse as [N][64]
    k_gemm<64, 1, 32, 64><<<dim3(gemmM, 1), 256, 0, stream>>>(
        mean, wlt2, hbuf, wrt2, 256, b2, 47, logits, N, 64);
    k_lsm<<<(N + 3) / 4, 256, 0, stream>>>(logits, N, out);
}

// Round 2
// 724.832 us; speedup vs baseline: 1.5660x; 1.5660x over previous
//
#include <hip/hip_runtime.h>
#include <hip/hip_bf16.h>
#include <math.h>

#define DEVFN __device__ __forceinline__

typedef unsigned int uint32;
typedef unsigned short ushort_t;

using bf16x8 = __attribute__((ext_vector_type(8))) short;
using f32x4  = __attribute__((ext_vector_type(4))) float;

DEVFN float bf2f(ushort_t u) {
    union { uint32 i; float f; } v; v.i = ((uint32)u) << 16; return v.f;
}
DEVFN ushort_t f2bf(float f) {
    union { float f; uint32 i; } v; v.f = f;
    uint32 u = v.i;
    uint32 r = (u + 0x7FFFu + ((u >> 16) & 1u)) >> 16;
    return (ushort_t)r;
}

DEVFN void gload_lds16(const void* g, void* l) {
    __builtin_amdgcn_global_load_lds(
        (const __attribute__((address_space(1))) void*)g,
        (__attribute__((address_space(3))) void*)l, 16, 0, 0);
}

// ---------- casts ----------
__global__ void k_cast_x(const float* __restrict__ x, ushort_t* __restrict__ xb, int N) {
    int total = N * 128;
    for (int i = blockIdx.x * blockDim.x + threadIdx.x; i < total; i += gridDim.x * blockDim.x) {
        int col = i & 127, row = i >> 7;
        float v = (col < 100) ? x[row * 100 + col] : 0.f;
        xb[i] = f2bf(v);
    }
}

// w: [K][Nout] row-major f32 -> wt: [Np][Kp] bf16 (transposed + zero-padded)
__global__ void k_cast_w(const float* __restrict__ w, ushort_t* __restrict__ wt,
                         int K, int Nout, int Kp, int Np) {
    int total = Np * Kp;
    for (int i = blockIdx.x * blockDim.x + threadIdx.x; i < total; i += gridDim.x * blockDim.x) {
        int k = i % Kp, n = i / Kp;
        float v = (k < K && n < Nout) ? w[k * Nout + n] : 0.f;
        wt[i] = f2bf(v);
    }
}

// ---------- CSR build ----------
__global__ void k_hist(const int* __restrict__ dst, int E, int* __restrict__ deg) {
    for (int i = blockIdx.x * blockDim.x + threadIdx.x; i < E; i += gridDim.x * blockDim.x)
        atomicAdd(&deg[dst[i]], 1);
}

__global__ void k_blocksum(const int* __restrict__ deg, int N, int* __restrict__ bsum) {
    __shared__ int s[1024];
    int i = blockIdx.x * 1024 + threadIdx.x;
    s[threadIdx.x] = (i < N) ? deg[i] : 0;
    __syncthreads();
    for (int o = 512; o > 0; o >>= 1) {
        if (threadIdx.x < o) s[threadIdx.x] += s[threadIdx.x + o];
        __syncthreads();
    }
    if (threadIdx.x == 0) bsum[blockIdx.x] = s[0];
}

__global__ void k_scanb(int* __restrict__ bsum, int NB) {
    if (blockIdx.x == 0 && threadIdx.x == 0) {
        int acc = 0;
        for (int i = 0; i < NB; ++i) { int v = bsum[i]; bsum[i] = acc; acc += v; }
    }
}

__global__ void k_offsets(const int* __restrict__ deg, const int* __restrict__ bsum,
                          int N, int* __restrict__ offs, int* __restrict__ cur) {
    __shared__ int s[1024];
    int t = threadIdx.x;
    int i = blockIdx.x * 1024 + t;
    int v = (i < N) ? deg[i] : 0;
    s[t] = v;
    __syncthreads();
    for (int o = 1; o < 1024; o <<= 1) {
        int add = (t >= o) ? s[t - o] : 0;
        __syncthreads();
        s[t] += add;
        __syncthreads();
    }
    int ex = s[t] - v + bsum[blockIdx.x];
    if (i < N) { offs[i] = ex; cur[i] = ex; }
}

__global__ void k_fill(const int* __restrict__ src, const int* __restrict__ dst, int E,
                       int* __restrict__ cur, int* __restrict__ csr) {
    for (int i = blockIdx.x * blockDim.x + threadIdx.x; i < E; i += gridDim.x * blockDim.x) {
        int d = dst[i];
        int slot = atomicAdd(&cur[d], 1);
        csr[slot] = src[i];
    }
}

// ---------- aggregation: one wave per node, mean of neighbor features ----------
// unroll-8: batch index loads then 8 independent gathers (8x memory-level parallelism)
template <int DIMS>
__global__ void k_agg(const ushort_t* __restrict__ h, const int* __restrict__ offs,
                      const int* __restrict__ deg, const int* __restrict__ csr,
                      int N, ushort_t* __restrict__ mean) {
    constexpr int VPL = DIMS / 64;  // bf16 per lane (2 or 4)
    int wid = (blockIdx.x * blockDim.x + threadIdx.x) >> 6;
    int lane = threadIdx.x & 63;
    if (wid >= N) return;
    int off = offs[wid], cnt = deg[wid];
    float acc[VPL] = {};
    const ushort_t* hp = h + (size_t)lane * VPL;
    int j = 0;
    if constexpr (VPL == 2) {
        for (; j + 8 <= cnt; j += 8) {
            int s[8];
#pragma unroll
            for (int u = 0; u < 8; ++u) s[u] = csr[off + j + u];
            uint32 d[8];
#pragma unroll
            for (int u = 0; u < 8; ++u) d[u] = *(const uint32*)(hp + (size_t)s[u] * DIMS);
#pragma unroll
            for (int u = 0; u < 8; ++u) {
                acc[0] += bf2f((ushort_t)(d[u] & 0xffff));
                acc[1] += bf2f((ushort_t)(d[u] >> 16));
            }
        }
        for (; j < cnt; ++j) {
            uint32 u = *(const uint32*)(hp + (size_t)csr[off + j] * DIMS);
            acc[0] += bf2f((ushort_t)(u & 0xffff));
            acc[1] += bf2f((ushort_t)(u >> 16));
        }
    } else {
        for (; j + 8 <= cnt; j += 8) {
            int s[8];
#pragma unroll
            for (int u = 0; u < 8; ++u) s[u] = csr[off + j + u];
            uint2 d[8];
#pragma unroll
            for (int u = 0; u < 8; ++u) d[u] = *(const uint2*)(hp + (size_t)s[u] * DIMS);
#pragma unroll
            for (int u = 0; u < 8; ++u) {
                acc[0] += bf2f((ushort_t)(d[u].x & 0xffff));
                acc[1] += bf2f((ushort_t)(d[u].x >> 16));
                acc[2] += bf2f((ushort_t)(d[u].y & 0xffff));
                acc[3] += bf2f((ushort_t)(d[u].y >> 16));
            }
        }
        for (; j < cnt; ++j) {
            uint2 u = *(const uint2*)(hp + (size_t)csr[off + j] * DIMS);
            acc[0] += bf2f((ushort_t)(u.x & 0xffff));
            acc[1] += bf2f((ushort_t)(u.x >> 16));
            acc[2] += bf2f((ushort_t)(u.y & 0xffff));
            acc[3] += bf2f((ushort_t)(u.y >> 16));
        }
    }
    float inv = 1.f / fmaxf((float)cnt, 1.f);
    if constexpr (VPL == 2) {
        uint32 o = (uint32)f2bf(acc[0] * inv) | ((uint32)f2bf(acc[1] * inv) << 16);
        *(uint32*)(mean + (size_t)wid * DIMS + lane * 2) = o;
    } else {
        uint2 o;
        o.x = (uint32)f2bf(acc[0] * inv) | ((uint32)f2bf(acc[1] * inv) << 16);
        o.y = (uint32)f2bf(acc[2] * inv) | ((uint32)f2bf(acc[3] * inv) << 16);
        *(uint2*)(mean + (size_t)wid * DIMS + lane * 4) = o;
    }
}

// ---------- MFMA GEMM ----------
// MODE 0 (layers 0/1): out = A1@B1^T + A2@B2^T, write bf16 [M][256], fused BN
//   column sum/sumsq -> stats (bias dropped: per-column constants cancel in BN).
// MODE 1 (layer 2):    out = A1@Bcat^T, cols 0..63 -> t2 bf16 [M][64],
//   cols 64..127 -> r2 fp32 [M][64] (+ bias).
template <int BN, int WAVES_N, int WM, int WN, int MODE>
__global__ __launch_bounds__(256) void k_gemm(
    const ushort_t* __restrict__ A1, const ushort_t* __restrict__ B1,
    const ushort_t* __restrict__ A2, const ushort_t* __restrict__ B2,
    int KP, const float* __restrict__ bias,
    ushort_t* __restrict__ out_bf, float* __restrict__ out_f,
    float* __restrict__ stats, int M) {
    constexpr int BM = 128, BK = 32;
    constexpr int M_REP = WM / 16, N_REP = WN / 16;
    constexpr int SIDES = (MODE == 0) ? 2 : 1;
    __shared__ ushort_t Alds[BM * BK];
    __shared__ ushort_t Blds[BN * BK];
    __shared__ float sstat[2][BN];
    const int tid = threadIdx.x, lane = tid & 63, wid = tid >> 6;
    const int wm = wid / WAVES_N, wn = wid % WAVES_N;
    const int row0 = blockIdx.x * BM, col0 = blockIdx.y * BN;
    if (MODE == 0) {
        for (int i = tid; i < 2 * BN; i += 256) (&sstat[0][0])[i] = 0.f;
    }
    f32x4 acc[M_REP][N_REP] = {};
    for (int side = 0; side < SIDES; ++side) {
        const ushort_t* A = side ? A2 : A1;
        const ushort_t* B = side ? B2 : B1;
        for (int kt = 0; kt < KP; kt += BK) {
            __syncthreads();  // protect LDS from prior iteration's readers
            for (int i = tid; i < BM * 4; i += 256) {
                int r = i >> 2, c = i & 3;
                int gr = row0 + r;
                if (gr >= M) gr = M - 1;
                gload_lds16(A + (size_t)gr * KP + kt + c * 8, Alds + i * 8);
            }
            for (int i = tid; i < BN * 4; i += 256) {
                int r = i >> 2, c = i & 3;
                gload_lds16(B + (size_t)(col0 + r) * KP + kt + c * 8, Blds + i * 8);
            }
            __syncthreads();
            bf16x8 a[M_REP], b[N_REP];
#pragma unroll
            for (int m = 0; m < M_REP; ++m)
                a[m] = *(const bf16x8*)&Alds[(wm * WM + m * 16 + (lane & 15)) * BK + (lane >> 4) * 8];
#pragma unroll
            for (int n = 0; n < N_REP; ++n)
                b[n] = *(const bf16x8*)&Blds[(wn * WN + n * 16 + (lane & 15)) * BK + (lane >> 4) * 8];
#pragma unroll
            for (int m = 0; m < M_REP; ++m)
#pragma unroll
                for (int n = 0; n < N_REP; ++n)
                    acc[m][n] = __builtin_amdgcn_mfma_f32_16x16x32_bf16(a[m], b[n], acc[m][n], 0, 0, 0);
        }
    }
#pragma unroll
    for (int n = 0; n < N_REP; ++n) {
        int lcol = wn * WN + n * 16 + (lane & 15);
        float s = 0.f, q = 0.f;
#pragma unroll
        for (int m = 0; m < M_REP; ++m) {
#pragma unroll
            for (int r = 0; r < 4; ++r) {
                int row = row0 + wm * WM + m * 16 + (lane >> 4) * 4 + r;
                float v = acc[m][n][r];
                if (row < M) {
                    if (MODE == 0) {
                        out_bf[(size_t)row * 256 + col0 + lcol] = f2bf(v);
                        s += v;
                        q += v * v;
                    } else {
                        if (lcol < 64) {
                            out_bf[(size_t)row * 64 + lcol] = f2bf(v);
                        } else {
                            int c = lcol - 64;
                            float bv = (c < 47) ? bias[c] : 0.f;
                            out_f[(size_t)row * 64 + c] = v + bv;
                        }
                    }
                }
            }
        }
        if (MODE == 0) {
            s += __shfl_xor(s, 16); s += __shfl_xor(s, 32);
            q += __shfl_xor(q, 16); q += __shfl_xor(q, 32);
            if (lane < 16) {
                atomicAdd(&sstat[0][lcol], s);
                atomicAdd(&sstat[1][lcol], q);
            }
        }
    }
    if (MODE == 0) {
        __syncthreads();
        for (int i = tid; i < BN; i += 256) {
            atomicAdd(&stats[col0 + i], sstat[0][i]);
            atomicAdd(&stats[256 + col0 + i], sstat[1][i]);
        }
    }
}

// ---------- BN apply + ReLU, bf16 in / bf16 out ----------
__global__ void k_bnrelu(const ushort_t* __restrict__ h, const float* __restrict__ stats,
                         const float* __restrict__ g, const float* __restrict__ be,
                         int M, ushort_t* __restrict__ out) {
    int c = threadIdx.x;
    float invM = 1.f / (float)M;
    float mean = stats[c] * invM;
    float var = stats[256 + c] * invM - mean * mean;
    float sc = g[c] * rsqrtf(var + 1e-5f);
    float sh = be[c] - mean * sc;
    for (int r = blockIdx.x; r < M; r += gridDim.x) {
        float v = bf2f(h[(size_t)r * 256 + c]) * sc + sh;
        out[(size_t)r * 256 + c] = f2bf(fmaxf(v, 0.f));
    }
}

// ---------- layer 2: aggregate 64-dim transformed feats + log_softmax ----------
__global__ void k_agg_lsm(const ushort_t* __restrict__ t2, const float* __restrict__ r2,
                          const int* __restrict__ offs, const int* __restrict__ deg,
                          const int* __restrict__ csr, int N, float* __restrict__ out) {
    int wid = (blockIdx.x * blockDim.x + threadIdx.x) >> 6;
    int lane = threadIdx.x & 63;
    if (wid >= N) return;
    int off = offs[wid], cnt = deg[wid];
    float acc = 0.f;
    const ushort_t* tp = t2 + lane;
    int j = 0;
    for (; j + 8 <= cnt; j += 8) {
        int s[8];
#pragma unroll
        for (int u = 0; u < 8; ++u) s[u] = csr[off + j + u];
        ushort_t d[8];
#pragma unroll
        for (int u = 0; u < 8; ++u) d[u] = tp[(size_t)s[u] * 64];
#pragma unroll
        for (int u = 0; u < 8; ++u) acc += bf2f(d[u]);
    }
    for (; j < cnt; ++j) acc += bf2f(tp[(size_t)csr[off + j] * 64]);
    float v = acc / fmaxf((float)cnt, 1.f) + r2[(size_t)wid * 64 + lane];
    if (lane >= 47) v = -1e30f;
    float m = v;
    for (int o = 32; o > 0; o >>= 1) m = fmaxf(m, __shfl_xor(m, o));
    float e = (lane < 47) ? expf(v - m) : 0.f;
    float sum = e;
    for (int o = 32; o > 0; o >>= 1) sum += __shfl_xor(sum, o);
    if (lane < 47) out[(size_t)wid * 47 + lane] = v - m - logf(sum);
}

extern "C" void kernel_launch(void* const* d_in, const int* in_sizes, int n_in,
                              void* d_out, int out_size, void* d_ws, size_t ws_size,
                              hipStream_t stream) {
    const float* x   = (const float*)d_in[0];
    const int*   ei  = (const int*)d_in[1];
    const float* wl0 = (const float*)d_in[2];
    const float* wr0 = (const float*)d_in[3];
    const float* g0  = (const float*)d_in[5];
    const float* be0 = (const float*)d_in[6];
    const float* wl1 = (const float*)d_in[7];
    const float* wr1 = (const float*)d_in[8];
    const float* g1  = (const float*)d_in[10];
    const float* be1 = (const float*)d_in[11];
    const float* wl2 = (const float*)d_in[12];
    const float* wr2 = (const float*)d_in[13];
    const float* b2  = (const float*)d_in[14];
    float* out = (float*)d_out;

    const int N = in_sizes[0] / 100;
    const int E = in_sizes[1] / 2;
    const int* src = ei;
    const int* dst = ei + E;

    // workspace carve (256B aligned)
    char* p = (char*)d_ws;
    auto alloc = [&](size_t bytes) -> char* {
        char* r = p;
        p += (bytes + 255) & ~(size_t)255;
        return r;
    };
    ushort_t* xb   = (ushort_t*)alloc((size_t)N * 128 * 2);
    ushort_t* hbuf = (ushort_t*)alloc((size_t)N * 256 * 2);
    ushort_t* mean = (ushort_t*)alloc((size_t)N * 256 * 2);
    ushort_t* hpre = (ushort_t*)alloc((size_t)N * 256 * 2);
    ushort_t* t2   = (ushort_t*)alloc((size_t)N * 64 * 2);
    float*    r2   = (float*)alloc((size_t)N * 64 * 4);
    int* deg  = (int*)alloc((size_t)N * 4);
    int* offs = (int*)alloc((size_t)N * 4);
    int* cur  = (int*)alloc((size_t)N * 4);
    int* csr  = (int*)alloc((size_t)E * 4);
    int* bsum = (int*)alloc(1024 * 4);
    float* stats = (float*)alloc(512 * 4);
    ushort_t* wlt0 = (ushort_t*)alloc(256 * 128 * 2);
    ushort_t* wrt0 = (ushort_t*)alloc(256 * 128 * 2);
    ushort_t* wlt1 = (ushort_t*)alloc(256 * 256 * 2);
    ushort_t* wrt1 = (ushort_t*)alloc(256 * 256 * 2);
    ushort_t* wcat2 = (ushort_t*)alloc(128 * 256 * 2);
    if ((size_t)(p - (char*)d_ws) > ws_size) return;  // insufficient scratch

    hipMemsetAsync(deg, 0, (size_t)N * 4, stream);

    k_cast_x<<<2048, 256, 0, stream>>>(x, xb, N);
    k_cast_w<<<128, 256, 0, stream>>>(wl0, wlt0, 100, 256, 128, 256);
    k_cast_w<<<128, 256, 0, stream>>>(wr0, wrt0, 100, 256, 128, 256);
    k_cast_w<<<128, 256, 0, stream>>>(wl1, wlt1, 256, 256, 256, 256);
    k_cast_w<<<128, 256, 0, stream>>>(wr1, wrt1, 256, 256, 256, 256);
    k_cast_w<<<128, 256, 0, stream>>>(wl2, wcat2, 256, 47, 256, 64);
    k_cast_w<<<128, 256, 0, stream>>>(wr2, wcat2 + 64 * 256, 256, 47, 256, 64);

    k_hist<<<2048, 256, 0, stream>>>(dst, E, deg);
    int NB = (N + 1023) / 1024;
    k_blocksum<<<NB, 1024, 0, stream>>>(deg, N, bsum);
    k_scanb<<<1, 64, 0, stream>>>(bsum, NB);
    k_offsets<<<NB, 1024, 0, stream>>>(deg, bsum, N, offs, cur);
    k_fill<<<2048, 256, 0, stream>>>(src, dst, E, cur, csr);

    int aggBlocks = (N + 3) / 4;      // 4 waves (nodes) per 256-thread block
    int gemmM = (N + 127) / 128;

    // ---- layer 0 ----
    k_agg<128><<<aggBlocks, 256, 0, stream>>>(xb, offs, deg, csr, N, mean);
    hipMemsetAsync(stats, 0, 512 * 4, stream);
    k_gemm<128, 2, 64, 64, 0><<<dim3(gemmM, 2), 256, 0, stream>>>(
        mean, wlt0, xb, wrt0, 128, nullptr, hpre, nullptr, stats, N);
    k_bnrelu<<<2048, 256, 0, stream>>>(hpre, stats, g0, be0, N, hbuf);

    // ---- layer 1 ----
    k_agg<256><<<aggBlocks, 256, 0, stream>>>(hbuf, offs, deg, csr, N, mean);
    hipMemsetAsync(stats, 0, 512 * 4, stream);
    k_gemm<128, 2, 64, 64, 0><<<dim3(gemmM, 2), 256, 0, stream>>>(
        mean, wlt1, hbuf, wrt1, 256, nullptr, hpre, nullptr, stats, N);
    k_bnrelu<<<2048, 256, 0, stream>>>(hpre, stats, g1, be1, N, hbuf);

    // ---- layer 2 (transform-first: mean(h)@wl2 == mean(h@wl2)) ----
    k_gemm<128, 2, 64, 64, 1><<<dim3(gemmM, 1), 256, 0, stream>>>(
        hbuf, wcat2, nullptr, nullptr, 256, b2, t2, r2, nullptr, N);
    k_agg_lsm<<<(N + 3) / 4, 256, 0, stream>>>(t2, r2, offs, deg, csr, N, out);
}

// Round 3
// 599.961 us; speedup vs baseline: 1.8920x; 1.2081x over previous
//
#include <hip/hip_runtime.h>
#include <hip/hip_bf16.h>
#include <math.h>

#define DEVFN __device__ __forceinline__

typedef unsigned int uint32;
typedef unsigned short ushort_t;

using bf16x8 = __attribute__((ext_vector_type(8))) short;
using f32x4  = __attribute__((ext_vector_type(4))) float;

DEVFN float bf2f(ushort_t u) {
    union { uint32 i; float f; } v; v.i = ((uint32)u) << 16; return v.f;
}
DEVFN ushort_t f2bf(float f) {
    union { float f; uint32 i; } v; v.f = f;
    uint32 u = v.i;
    uint32 r = (u + 0x7FFFu + ((u >> 16) & 1u)) >> 16;
    return (ushort_t)r;
}

DEVFN void gload_lds16(const void* g, void* l) {
    __builtin_amdgcn_global_load_lds(
        (const __attribute__((address_space(1))) void*)g,
        (__attribute__((address_space(3))) void*)l, 16, 0, 0);
}

// ---------- casts ----------
__global__ void k_cast_x(const float* __restrict__ x, ushort_t* __restrict__ xb, int N) {
    int total = N * 128;
    for (int i = blockIdx.x * blockDim.x + threadIdx.x; i < total; i += gridDim.x * blockDim.x) {
        int col = i & 127, row = i >> 7;
        float v = (col < 100) ? x[row * 100 + col] : 0.f;
        xb[i] = f2bf(v);
    }
}

// w: [K][Nout] row-major f32 -> wt: [Np][Kp] bf16 (transposed + zero-padded)
__global__ void k_cast_w(const float* __restrict__ w, ushort_t* __restrict__ wt,
                         int K, int Nout, int Kp, int Np) {
    int total = Np * Kp;
    for (int i = blockIdx.x * blockDim.x + threadIdx.x; i < total; i += gridDim.x * blockDim.x) {
        int k = i % Kp, n = i / Kp;
        float v = (k < K && n < Nout) ? w[k * Nout + n] : 0.f;
        wt[i] = f2bf(v);
    }
}

// ---------- CSR build v2: binned counting sort by dst>>10 ----------
// Pass 1: per-(bin, block) histogram. LDS hist, 128 blocks x CH-edge chunks.
__global__ void k_bincount(const int* __restrict__ dst, int E, int CH, int nbins, int nblk,
                           int* __restrict__ binCnt) {
    __shared__ int scnt[128];
    int blk = blockIdx.x, tid = threadIdx.x;
    for (int b = tid; b < 128; b += 256) scnt[b] = 0;
    __syncthreads();
    int e0 = blk * CH, e1 = min(E, e0 + CH);
    for (int i = e0 + tid; i < e1; i += 256)
        atomicAdd(&scnt[dst[i] >> 10], 1);
    __syncthreads();
    for (int b = tid; b < nbins; b += 256) binCnt[b * nblk + blk] = scnt[b];
}

// generic scan helpers (reused for the 12.5K-entry bin-count scan)
__global__ void k_blocksum(const int* __restrict__ v, int n, int* __restrict__ bsum) {
    __shared__ int s[1024];
    int i = blockIdx.x * 1024 + threadIdx.x;
    s[threadIdx.x] = (i < n) ? v[i] : 0;
    __syncthreads();
    for (int o = 512; o > 0; o >>= 1) {
        if (threadIdx.x < o) s[threadIdx.x] += s[threadIdx.x + o];
        __syncthreads();
    }
    if (threadIdx.x == 0) bsum[blockIdx.x] = s[0];
}

__global__ void k_scanb(int* __restrict__ bsum, int NB) {
    if (blockIdx.x == 0 && threadIdx.x == 0) {
        int acc = 0;
        for (int i = 0; i < NB; ++i) { int v = bsum[i]; bsum[i] = acc; acc += v; }
    }
}

__global__ void k_exscan(const int* __restrict__ v, const int* __restrict__ bsum,
                         int n, int* __restrict__ outOff) {
    __shared__ int s[1024];
    int t = threadIdx.x;
    int i = blockIdx.x * 1024 + t;
    int val = (i < n) ? v[i] : 0;
    s[t] = val;
    __syncthreads();
    for (int o = 1; o < 1024; o <<= 1) {
        int add = (t >= o) ? s[t - o] : 0;
        __syncthreads();
        s[t] += add;
        __syncthreads();
    }
    if (i < n) outOff[i] = s[t] - val + bsum[blockIdx.x];
}

// Pass 2: scatter packed edges into bin-partitioned array (coalesced-ish runs).
__global__ void k_binscatter(const int* __restrict__ src, const int* __restrict__ dst,
                             int E, int CH, int nbins, int nblk,
                             const int* __restrict__ binOff, int* __restrict__ ebin) {
    __shared__ int scur[128];
    int blk = blockIdx.x, tid = threadIdx.x;
    for (int b = tid; b < nbins; b += 256) scur[b] = binOff[b * nblk + blk];
    __syncthreads();
    int e0 = blk * CH, e1 = min(E, e0 + CH);
    for (int i = e0 + tid; i < e1; i += 256) {
        int d = dst[i];
        int b = d >> 10;
        int pos = atomicAdd(&scur[b], 1);
        ebin[pos] = (src[i] << 10) | (d & 1023);
    }
}

// Pass 3: per-bin CSR finalize. LDS degree count + scan + local scatter.
__global__ void k_bincsr(const int* __restrict__ ebin, const int* __restrict__ binOff,
                         int E, int N, int nbins, int nblk,
                         int* __restrict__ offs, int* __restrict__ deg, int* __restrict__ csr) {
    __shared__ int sdeg[1024];
    __shared__ int scur[1024];
    int bin = blockIdx.x, t = threadIdx.x;
    int binStart = binOff[bin * nblk];
    int binEnd = (bin + 1 < nbins) ? binOff[(bin + 1) * nblk] : E;
    sdeg[t] = 0;
    __syncthreads();
    for (int i = binStart + t; i < binEnd; i += 1024)
        atomicAdd(&sdeg[ebin[i] & 1023], 1);
    __syncthreads();
    int v = sdeg[t];
    for (int o = 1; o < 1024; o <<= 1) {
        int add = (t >= o) ? sdeg[t - o] : 0;
        __syncthreads();
        sdeg[t] += add;
        __syncthreads();
    }
    int ex = sdeg[t] - v;
    int node = bin * 1024 + t;
    if (node < N) { offs[node] = binStart + ex; deg[node] = v; }
    scur[t] = ex;
    __syncthreads();
    for (int i = binStart + t; i < binEnd; i += 1024) {
        int e = ebin[i];
        int slot = atomicAdd(&scur[e & 1023], 1);
        csr[binStart + slot] = e >> 10;
    }
}

// ---------- aggregation: one wave per node, mean of neighbor features ----------
template <int DIMS>
__global__ void k_agg(const ushort_t* __restrict__ h, const int* __restrict__ offs,
                      const int* __restrict__ deg, const int* __restrict__ csr,
                      int N, ushort_t* __restrict__ mean) {
    constexpr int VPL = DIMS / 64;  // bf16 per lane (2 or 4)
    int wid = (blockIdx.x * blockDim.x + threadIdx.x) >> 6;
    int lane = threadIdx.x & 63;
    if (wid >= N) return;
    int off = offs[wid], cnt = deg[wid];
    float acc[VPL] = {};
    const ushort_t* hp = h + (size_t)lane * VPL;
    int j = 0;
    if constexpr (VPL == 2) {
        for (; j + 8 <= cnt; j += 8) {
            int s[8];
#pragma unroll
            for (int u = 0; u < 8; ++u) s[u] = csr[off + j + u];
            uint32 d[8];
#pragma unroll
            for (int u = 0; u < 8; ++u) d[u] = *(const uint32*)(hp + (size_t)s[u] * DIMS);
#pragma unroll
            for (int u = 0; u < 8; ++u) {
                acc[0] += bf2f((ushort_t)(d[u] & 0xffff));
                acc[1] += bf2f((ushort_t)(d[u] >> 16));
            }
        }
        for (; j < cnt; ++j) {
            uint32 u = *(const uint32*)(hp + (size_t)csr[off + j] * DIMS);
            acc[0] += bf2f((ushort_t)(u & 0xffff));
            acc[1] += bf2f((ushort_t)(u >> 16));
        }
    } else {
        for (; j + 8 <= cnt; j += 8) {
            int s[8];
#pragma unroll
            for (int u = 0; u < 8; ++u) s[u] = csr[off + j + u];
            uint2 d[8];
#pragma unroll
            for (int u = 0; u < 8; ++u) d[u] = *(const uint2*)(hp + (size_t)s[u] * DIMS);
#pragma unroll
            for (int u = 0; u < 8; ++u) {
                acc[0] += bf2f((ushort_t)(d[u].x & 0xffff));
                acc[1] += bf2f((ushort_t)(d[u].x >> 16));
                acc[2] += bf2f((ushort_t)(d[u].y & 0xffff));
                acc[3] += bf2f((ushort_t)(d[u].y >> 16));
            }
        }
        for (; j < cnt; ++j) {
            uint2 u = *(const uint2*)(hp + (size_t)csr[off + j] * DIMS);
            acc[0] += bf2f((ushort_t)(u.x & 0xffff));
            acc[1] += bf2f((ushort_t)(u.x >> 16));
            acc[2] += bf2f((ushort_t)(u.y & 0xffff));
            acc[3] += bf2f((ushort_t)(u.y >> 16));
        }
    }
    float inv = 1.f / fmaxf((float)cnt, 1.f);
    if constexpr (VPL == 2) {
        uint32 o = (uint32)f2bf(acc[0] * inv) | ((uint32)f2bf(acc[1] * inv) << 16);
        *(uint32*)(mean + (size_t)wid * DIMS + lane * 2) = o;
    } else {
        uint2 o;
        o.x = (uint32)f2bf(acc[0] * inv) | ((uint32)f2bf(acc[1] * inv) << 16);
        o.y = (uint32)f2bf(acc[2] * inv) | ((uint32)f2bf(acc[3] * inv) << 16);
        *(uint2*)(mean + (size_t)wid * DIMS + lane * 4) = o;
    }
}

// ---------- MFMA GEMM ----------
// MODE 0 (layers 0/1): out = A1@B1^T + A2@B2^T, write bf16 [M][256], fused BN
//   column sum/sumsq -> stats (bias dropped: per-column constants cancel in BN).
// MODE 1 (layer 2):    out = A1@Bcat^T, cols 0..63 -> t2 bf16 [M][64],
//   cols 64..127 -> r2 fp32 [M][64] (+ bias).
template <int BN, int WAVES_N, int WM, int WN, int MODE>
__global__ __launch_bounds__(256) void k_gemm(
    const ushort_t* __restrict__ A1, const ushort_t* __restrict__ B1,
    const ushort_t* __restrict__ A2, const ushort_t* __restrict__ B2,
    int KP, const float* __restrict__ bias,
    ushort_t* __restrict__ out_bf, float* __restrict__ out_f,
    float* __restrict__ stats, int M) {
    constexpr int BM = 128, BK = 32;
    constexpr int M_REP = WM / 16, N_REP = WN / 16;
    constexpr int SIDES = (MODE == 0) ? 2 : 1;
    __shared__ ushort_t Alds[BM * BK];
    __shared__ ushort_t Blds[BN * BK];
    __shared__ float sstat[2][BN];
    const int tid = threadIdx.x, lane = tid & 63, wid = tid >> 6;
    const int wm = wid / WAVES_N, wn = wid % WAVES_N;
    const int row0 = blockIdx.x * BM, col0 = blockIdx.y * BN;
    if (MODE == 0) {
        for (int i = tid; i < 2 * BN; i += 256) (&sstat[0][0])[i] = 0.f;
    }
    f32x4 acc[M_REP][N_REP] = {};
    for (int side = 0; side < SIDES; ++side) {
        const ushort_t* A = side ? A2 : A1;
        const ushort_t* B = side ? B2 : B1;
        for (int kt = 0; kt < KP; kt += BK) {
            __syncthreads();  // protect LDS from prior iteration's readers
            for (int i = tid; i < BM * 4; i += 256) {
                int r = i >> 2, c = i & 3;
                int gr = row0 + r;
                if (gr >= M) gr = M - 1;
                gload_lds16(A + (size_t)gr * KP + kt + c * 8, Alds + i * 8);
            }
            for (int i = tid; i < BN * 4; i += 256) {
                int r = i >> 2, c = i & 3;
                gload_lds16(B + (size_t)(col0 + r) * KP + kt + c * 8, Blds + i * 8);
            }
            __syncthreads();
            bf16x8 a[M_REP], b[N_REP];
#pragma unroll
            for (int m = 0; m < M_REP; ++m)
                a[m] = *(const bf16x8*)&Alds[(wm * WM + m * 16 + (lane & 15)) * BK + (lane >> 4) * 8];
#pragma unroll
            for (int n = 0; n < N_REP; ++n)
                b[n] = *(const bf16x8*)&Blds[(wn * WN + n * 16 + (lane & 15)) * BK + (lane >> 4) * 8];
#pragma unroll
            for (int m = 0; m < M_REP; ++m)
#pragma unroll
                for (int n = 0; n < N_REP; ++n)
                    acc[m][n] = __builtin_amdgcn_mfma_f32_16x16x32_bf16(a[m], b[n], acc[m][n], 0, 0, 0);
        }
    }
#pragma unroll
    for (int n = 0; n < N_REP; ++n) {
        int lcol = wn * WN + n * 16 + (lane & 15);
        float s = 0.f, q = 0.f;
#pragma unroll
        for (int m = 0; m < M_REP; ++m) {
#pragma unroll
            for (int r = 0; r < 4; ++r) {
                int row = row0 + wm * WM + m * 16 + (lane >> 4) * 4 + r;
                float v = acc[m][n][r];
                if (row < M) {
                    if (MODE == 0) {
                        out_bf[(size_t)row * 256 + col0 + lcol] = f2bf(v);
                        s += v;
                        q += v * v;
                    } else {
                        if (lcol < 64) {
                            out_bf[(size_t)row * 64 + lcol] = f2bf(v);
                        } else {
                            int c = lcol - 64;
                            float bv = (c < 47) ? bias[c] : 0.f;
                            out_f[(size_t)row * 64 + c] = v + bv;
                        }
                    }
                }
            }
        }
        if (MODE == 0) {
            s += __shfl_xor(s, 16); s += __shfl_xor(s, 32);
            q += __shfl_xor(q, 16); q += __shfl_xor(q, 32);
            if (lane < 16) {
                atomicAdd(&sstat[0][lcol], s);
                atomicAdd(&sstat[1][lcol], q);
            }
        }
    }
    if (MODE == 0) {
        __syncthreads();
        for (int i = tid; i < BN; i += 256) {
            atomicAdd(&stats[col0 + i], sstat[0][i]);
            atomicAdd(&stats[256 + col0 + i], sstat[1][i]);
        }
    }
}

// ---------- BN apply + ReLU, bf16 in / bf16 out ----------
__global__ void k_bnrelu(const ushort_t* __restrict__ h, const float* __restrict__ stats,
                         const float* __restrict__ g, const float* __restrict__ be,
                         int M, ushort_t* __restrict__ out) {
    int c = threadIdx.x;
    float invM = 1.f / (float)M;
    float mean = stats[c] * invM;
    float var = stats[256 + c] * invM - mean * mean;
    float sc = g[c] * rsqrtf(var + 1e-5f);
    float sh = be[c] - mean * sc;
    for (int r = blockIdx.x; r < M; r += gridDim.x) {
        float v = bf2f(h[(size_t)r * 256 + c]) * sc + sh;
        out[(size_t)r * 256 + c] = f2bf(fmaxf(v, 0.f));
    }
}

// ---------- layer 2: aggregate 64-dim transformed feats + log_softmax ----------
__global__ void k_agg_lsm(const ushort_t* __restrict__ t2, const float* __restrict__ r2,
                          const int* __restrict__ offs, const int* __restrict__ deg,
                          const int* __restrict__ csr, int N, float* __restrict__ out) {
    int wid = (blockIdx.x * blockDim.x + threadIdx.x) >> 6;
    int lane = threadIdx.x & 63;
    if (wid >= N) return;
    int off = offs[wid], cnt = deg[wid];
    float acc = 0.f;
    const ushort_t* tp = t2 + lane;
    int j = 0;
    for (; j + 8 <= cnt; j += 8) {
        int s[8];
#pragma unroll
        for (int u = 0; u < 8; ++u) s[u] = csr[off + j + u];
        ushort_t d[8];
#pragma unroll
        for (int u = 0; u < 8; ++u) d[u] = tp[(size_t)s[u] * 64];
#pragma unroll
        for (int u = 0; u < 8; ++u) acc += bf2f(d[u]);
    }
    for (; j < cnt; ++j) acc += bf2f(tp[(size_t)csr[off + j] * 64]);
    float v = acc / fmaxf((float)cnt, 1.f) + r2[(size_t)wid * 64 + lane];
    if (lane >= 47) v = -1e30f;
    float m = v;
    for (int o = 32; o > 0; o >>= 1) m = fmaxf(m, __shfl_xor(m, o));
    float e = (lane < 47) ? expf(v - m) : 0.f;
    float sum = e;
    for (int o = 32; o > 0; o >>= 1) sum += __shfl_xor(sum, o);
    if (lane < 47) out[(size_t)wid * 47 + lane] = v - m - logf(sum);
}

extern "C" void kernel_launch(void* const* d_in, const int* in_sizes, int n_in,
                              void* d_out, int out_size, void* d_ws, size_t ws_size,
                              hipStream_t stream) {
    const float* x   = (const float*)d_in[0];
    const int*   ei  = (const int*)d_in[1];
    const float* wl0 = (const float*)d_in[2];
    const float* wr0 = (const float*)d_in[3];
    const float* g0  = (const float*)d_in[5];
    const float* be0 = (const float*)d_in[6];
    const float* wl1 = (const float*)d_in[7];
    const float* wr1 = (const float*)d_in[8];
    const float* g1  = (const float*)d_in[10];
    const float* be1 = (const float*)d_in[11];
    const float* wl2 = (const float*)d_in[12];
    const float* wr2 = (const float*)d_in[13];
    const float* b2  = (const float*)d_in[14];
    float* out = (float*)d_out;

    const int N = in_sizes[0] / 100;
    const int E = in_sizes[1] / 2;
    const int* src = ei;
    const int* dst = ei + E;

    // workspace carve (256B aligned)
    char* p = (char*)d_ws;
    auto alloc = [&](size_t bytes) -> char* {
        char* r = p;
        p += (bytes + 255) & ~(size_t)255;
        return r;
    };
    ushort_t* xb   = (ushort_t*)alloc((size_t)N * 128 * 2);
    ushort_t* hbuf = (ushort_t*)alloc((size_t)N * 256 * 2);
    ushort_t* mean = (ushort_t*)alloc((size_t)N * 256 * 2);
    ushort_t* hpre = (ushort_t*)alloc((size_t)N * 256 * 2);
    int* deg  = (int*)alloc((size_t)N * 4);
    int* offs = (int*)alloc((size_t)N * 4);
    int* csr  = (int*)alloc((size_t)E * 4);
    int* ebin = (int*)alloc((size_t)E * 4);
    // bin-count scan arrays
    const int NBLK = 128;
    const int nbins = (N + 1023) >> 10;           // 98 for N=100000
    const int scanN = nbins * NBLK;
    int* binCnt = (int*)alloc((size_t)scanN * 4);
    int* binOff = (int*)alloc((size_t)scanN * 4);
    int* bsum = (int*)alloc(1024 * 4);
    float* stats = (float*)alloc(512 * 4);
    ushort_t* wlt0 = (ushort_t*)alloc(256 * 128 * 2);
    ushort_t* wrt0 = (ushort_t*)alloc(256 * 128 * 2);
    ushort_t* wlt1 = (ushort_t*)alloc(256 * 256 * 2);
    ushort_t* wrt1 = (ushort_t*)alloc(256 * 256 * 2);
    ushort_t* wcat2 = (ushort_t*)alloc(128 * 256 * 2);
    if ((size_t)(p - (char*)d_ws) > ws_size) return;  // insufficient scratch

    // layer-2 buffers alias `mean` (unused after layer-1 GEMM)
    ushort_t* t2 = mean;                               // [N][64] bf16
    float*    r2 = (float*)((char*)mean + (size_t)N * 64 * 2);  // [N][64] f32

    k_cast_x<<<2048, 256, 0, stream>>>(x, xb, N);
    k_cast_w<<<128, 256, 0, stream>>>(wl0, wlt0, 100, 256, 128, 256);
    k_cast_w<<<128, 256, 0, stream>>>(wr0, wrt0, 100, 256, 128, 256);
    k_cast_w<<<128, 256, 0, stream>>>(wl1, wlt1, 256, 256, 256, 256);
    k_cast_w<<<128, 256, 0, stream>>>(wr1, wrt1, 256, 256, 256, 256);
    k_cast_w<<<128, 256, 0, stream>>>(wl2, wcat2, 256, 47, 256, 64);
    k_cast_w<<<128, 256, 0, stream>>>(wr2, wcat2 + 64 * 256, 256, 47, 256, 64);

    // ---- CSR build v2 (binned counting sort) ----
    const int CH = (E + NBLK - 1) / NBLK;
    k_bincount<<<NBLK, 256, 0, stream>>>(dst, E, CH, nbins, NBLK, binCnt);
    int NB2 = (scanN + 1023) / 1024;
    k_blocksum<<<NB2, 1024, 0, stream>>>(binCnt, scanN, bsum);
    k_scanb<<<1, 64, 0, stream>>>(bsum, NB2);
    k_exscan<<<NB2, 1024, 0, stream>>>(binCnt, bsum, scanN, binOff);
    k_binscatter<<<NBLK, 256, 0, stream>>>(src, dst, E, CH, nbins, NBLK, binOff, ebin);
    k_bincsr<<<nbins, 1024, 0, stream>>>(ebin, binOff, E, N, nbins, NBLK, offs, deg, csr);

    int aggBlocks = (N + 3) / 4;      // 4 waves (nodes) per 256-thread block
    int gemmM = (N + 127) / 128;

    // ---- layer 0 ----
    k_agg<128><<<aggBlocks, 256, 0, stream>>>(xb, offs, deg, csr, N, mean);
    hipMemsetAsync(stats, 0, 512 * 4, stream);
    k_gemm<128, 2, 64, 64, 0><<<dim3(gemmM, 2), 256, 0, stream>>>(
        mean, wlt0, xb, wrt0, 128, nullptr, hpre, nullptr, stats, N);
    k_bnrelu<<<2048, 256, 0, stream>>>(hpre, stats, g0, be0, N, hbuf);

    // ---- layer 1 ----
    k_agg<256><<<aggBlocks, 256, 0, stream>>>(hbuf, offs, deg, csr, N, mean);
    hipMemsetAsync(stats, 0, 512 * 4, stream);
    k_gemm<128, 2, 64, 64, 0><<<dim3(gemmM, 2), 256, 0, stream>>>(
        mean, wlt1, hbuf, wrt1, 256, nullptr, hpre, nullptr, stats, N);
    k_bnrelu<<<2048, 256, 0, stream>>>(hpre, stats, g1, be1, N, hbuf);

    // ---- layer 2 (transform-first: mean(h)@wl2 == mean(h@wl2)) ----
    k_gemm<128, 2, 64, 64, 1><<<dim3(gemmM, 1), 256, 0, stream>>>(
        hbuf, wcat2, nullptr, nullptr, 256, b2, t2, r2, nullptr, N);
    k_agg_lsm<<<(N + 3) / 4, 256, 0, stream>>>(t2, r2, offs, deg, csr, N, out);
}

// Round 4
// 580.936 us; speedup vs baseline: 1.9539x; 1.0327x over previous
//
#include <hip/hip_runtime.h>
#include <hip/hip_bf16.h>
#include <math.h>

#define DEVFN __device__ __forceinline__

typedef unsigned int uint32;
typedef unsigned short ushort_t;

using bf16x8 = __attribute__((ext_vector_type(8))) short;
using f32x4  = __attribute__((ext_vector_type(4))) float;

DEVFN float bf2f(ushort_t u) {
    union { uint32 i; float f; } v; v.i = ((uint32)u) << 16; return v.f;
}
DEVFN ushort_t f2bf(float f) {
    union { float f; uint32 i; } v; v.f = f;
    uint32 u = v.i;
    uint32 r = (u + 0x7FFFu + ((u >> 16) & 1u)) >> 16;
    return (ushort_t)r;
}

DEVFN void gload_lds16(const void* g, void* l) {
    __builtin_amdgcn_global_load_lds(
        (const __attribute__((address_space(1))) void*)g,
        (__attribute__((address_space(3))) void*)l, 16, 0, 0);
}

// ---------- casts ----------
__global__ void k_cast_x(const float* __restrict__ x, ushort_t* __restrict__ xb, int N) {
    int total = N * 128;
    for (int i = blockIdx.x * blockDim.x + threadIdx.x; i < total; i += gridDim.x * blockDim.x) {
        int col = i & 127, row = i >> 7;
        float v = (col < 100) ? x[row * 100 + col] : 0.f;
        xb[i] = f2bf(v);
    }
}

// w: [K][Nout] row-major f32 -> wt: [Np][Kp] bf16 (transposed + zero-padded)
__global__ void k_cast_w(const float* __restrict__ w, ushort_t* __restrict__ wt,
                         int K, int Nout, int Kp, int Np) {
    int total = Np * Kp;
    for (int i = blockIdx.x * blockDim.x + threadIdx.x; i < total; i += gridDim.x * blockDim.x) {
        int k = i % Kp, n = i / Kp;
        float v = (k < K && n < Nout) ? w[k * Nout + n] : 0.f;
        wt[i] = f2bf(v);
    }
}

// ---------- CSR build: binned counting sort by dst>>10 ----------
__global__ void k_bincount(const int* __restrict__ dst, int E, int CH, int nbins, int nblk,
                           int* __restrict__ binCnt) {
    __shared__ int scnt[128];
    int blk = blockIdx.x, tid = threadIdx.x;
    for (int b = tid; b < 128; b += 256) scnt[b] = 0;
    __syncthreads();
    int e0 = blk * CH, e1 = min(E, e0 + CH);
    for (int i = e0 + tid; i < e1; i += 256)
        atomicAdd(&scnt[dst[i] >> 10], 1);
    __syncthreads();
    for (int b = tid; b < nbins; b += 256) binCnt[b * nblk + blk] = scnt[b];
}

__global__ void k_blocksum(const int* __restrict__ v, int n, int* __restrict__ bsum) {
    __shared__ int s[1024];
    int i = blockIdx.x * 1024 + threadIdx.x;
    s[threadIdx.x] = (i < n) ? v[i] : 0;
    __syncthreads();
    for (int o = 512; o > 0; o >>= 1) {
        if (threadIdx.x < o) s[threadIdx.x] += s[threadIdx.x + o];
        __syncthreads();
    }
    if (threadIdx.x == 0) bsum[blockIdx.x] = s[0];
}

__global__ void k_scanb(int* __restrict__ bsum, int NB) {
    if (blockIdx.x == 0 && threadIdx.x == 0) {
        int acc = 0;
        for (int i = 0; i < NB; ++i) { int v = bsum[i]; bsum[i] = acc; acc += v; }
    }
}

__global__ void k_exscan(const int* __restrict__ v, const int* __restrict__ bsum,
                         int n, int* __restrict__ outOff) {
    __shared__ int s[1024];
    int t = threadIdx.x;
    int i = blockIdx.x * 1024 + t;
    int val = (i < n) ? v[i] : 0;
    s[t] = val;
    __syncthreads();
    for (int o = 1; o < 1024; o <<= 1) {
        int add = (t >= o) ? s[t - o] : 0;
        __syncthreads();
        s[t] += add;
        __syncthreads();
    }
    if (i < n) outOff[i] = s[t] - val + bsum[blockIdx.x];
}

__global__ void k_binscatter(const int* __restrict__ src, const int* __restrict__ dst,
                             int E, int CH, int nbins, int nblk,
                             const int* __restrict__ binOff, int* __restrict__ ebin) {
    __shared__ int scur[128];
    int blk = blockIdx.x, tid = threadIdx.x;
    for (int b = tid; b < nbins; b += 256) scur[b] = binOff[b * nblk + blk];
    __syncthreads();
    int e0 = blk * CH, e1 = min(E, e0 + CH);
    for (int i = e0 + tid; i < e1; i += 256) {
        int d = dst[i];
        int b = d >> 10;
        int pos = atomicAdd(&scur[b], 1);
        ebin[pos] = (src[i] << 10) | (d & 1023);
    }
}

__global__ void k_bincsr(const int* __restrict__ ebin, const int* __restrict__ binOff,
                         int E, int N, int nbins, int nblk,
                         int* __restrict__ offs, int* __restrict__ deg, int* __restrict__ csr) {
    __shared__ int sdeg[1024];
    __shared__ int scur[1024];
    int bin = blockIdx.x, t = threadIdx.x;
    int binStart = binOff[bin * nblk];
    int binEnd = (bin + 1 < nbins) ? binOff[(bin + 1) * nblk] : E;
    sdeg[t] = 0;
    __syncthreads();
    for (int i = binStart + t; i < binEnd; i += 1024)
        atomicAdd(&sdeg[ebin[i] & 1023], 1);
    __syncthreads();
    int v = sdeg[t];
    for (int o = 1; o < 1024; o <<= 1) {
        int add = (t >= o) ? sdeg[t - o] : 0;
        __syncthreads();
        sdeg[t] += add;
        __syncthreads();
    }
    int ex = sdeg[t] - v;
    int node = bin * 1024 + t;
    if (node < N) { offs[node] = binStart + ex; deg[node] = v; }
    scur[t] = ex;
    __syncthreads();
    for (int i = binStart + t; i < binEnd; i += 1024) {
        int e = ebin[i];
        int slot = atomicAdd(&scur[e & 1023], 1);
        csr[binStart + slot] = e >> 10;
    }
}

// ---------- aggregation: one wave per node, masked batches + idx prefetch ----------
template <int DIMS, int BATCH>
__global__ void k_agg(const ushort_t* __restrict__ h, const int* __restrict__ offs,
                      const int* __restrict__ deg, const int* __restrict__ csr,
                      int N, ushort_t* __restrict__ mean) {
    constexpr int VPL = DIMS / 64;  // bf16 per lane (2 or 4)
    int wid = (blockIdx.x * blockDim.x + threadIdx.x) >> 6;
    int lane = threadIdx.x & 63;
    if (wid >= N) return;
    int off = offs[wid], cnt = deg[wid];
    float acc[VPL] = {};
    const ushort_t* hp = h + (size_t)lane * VPL;
    if (cnt > 0) {
        int idx[BATCH];
#pragma unroll
        for (int u = 0; u < BATCH; ++u) idx[u] = csr[off + min(u, cnt - 1)];
        for (int b = 0; b < cnt; b += BATCH) {
            if constexpr (VPL == 2) {
                uint32 d[BATCH];
#pragma unroll
                for (int u = 0; u < BATCH; ++u)
                    d[u] = *(const uint32*)(hp + (size_t)idx[u] * DIMS);
                int nxt = b + BATCH;
#pragma unroll
                for (int u = 0; u < BATCH; ++u) idx[u] = csr[off + min(nxt + u, cnt - 1)];
#pragma unroll
                for (int u = 0; u < BATCH; ++u) {
                    float w = (b + u < cnt) ? 1.f : 0.f;
                    acc[0] += w * bf2f((ushort_t)(d[u] & 0xffff));
                    acc[1] += w * bf2f((ushort_t)(d[u] >> 16));
                }
            } else {
                uint2 d[BATCH];
#pragma unroll
                for (int u = 0; u < BATCH; ++u)
                    d[u] = *(const uint2*)(hp + (size_t)idx[u] * DIMS);
                int nxt = b + BATCH;
#pragma unroll
                for (int u = 0; u < BATCH; ++u) idx[u] = csr[off + min(nxt + u, cnt - 1)];
#pragma unroll
                for (int u = 0; u < BATCH; ++u) {
                    float w = (b + u < cnt) ? 1.f : 0.f;
                    acc[0] += w * bf2f((ushort_t)(d[u].x & 0xffff));
                    acc[1] += w * bf2f((ushort_t)(d[u].x >> 16));
                    acc[2] += w * bf2f((ushort_t)(d[u].y & 0xffff));
                    acc[3] += w * bf2f((ushort_t)(d[u].y >> 16));
                }
            }
        }
    }
    float inv = 1.f / fmaxf((float)cnt, 1.f);
    if constexpr (VPL == 2) {
        uint32 o = (uint32)f2bf(acc[0] * inv) | ((uint32)f2bf(acc[1] * inv) << 16);
        *(uint32*)(mean + (size_t)wid * DIMS + lane * 2) = o;
    } else {
        uint2 o;
        o.x = (uint32)f2bf(acc[0] * inv) | ((uint32)f2bf(acc[1] * inv) << 16);
        o.y = (uint32)f2bf(acc[2] * inv) | ((uint32)f2bf(acc[3] * inv) << 16);
        *(uint2*)(mean + (size_t)wid * DIMS + lane * 4) = o;
    }
}

// ---------- MFMA GEMM: 128-row tile x ALL output cols (single col-block) ----------
// MODE 0: out = A1@B1^T + A2@B2^T, bf16 [M][256], fused BN column sum/sumsq.
// MODE 1: out = A1@B1^T; cols 0..63 -> bf16 t2 [M][64], 64..127 -> f32 r2 [M][64] (+bias).
// 512 threads = 8 waves (WROWS x WCOLS).
template <int BN, int WROWS, int WCOLS, int MODE>
__global__ __launch_bounds__(512) void k_gemm(
    const ushort_t* __restrict__ A1, const ushort_t* __restrict__ B1,
    const ushort_t* __restrict__ A2, const ushort_t* __restrict__ B2,
    int KP, const float* __restrict__ bias,
    ushort_t* __restrict__ out_bf, float* __restrict__ out_f,
    float* __restrict__ stats, int M) {
    constexpr int BM = 128, BK = 64;
    constexpr int WM = BM / WROWS, WN = BN / WCOLS;
    constexpr int M_REP = WM / 16, N_REP = WN / 16;
    constexpr int SIDES = (MODE == 0) ? 2 : 1;
    __shared__ ushort_t Alds[BM * BK];
    __shared__ ushort_t Blds[BN * BK];
    __shared__ float sstat[2][BN];
    const int tid = threadIdx.x, lane = tid & 63, wid = tid >> 6;
    const int wm = wid / WCOLS, wn = wid % WCOLS;
    const int row0 = blockIdx.x * BM;
    if (MODE == 0) {
        for (int i = tid; i < 2 * BN; i += 512) (&sstat[0][0])[i] = 0.f;
    }
    f32x4 acc[M_REP][N_REP] = {};
    for (int side = 0; side < SIDES; ++side) {
        const ushort_t* A = side ? A2 : A1;
        const ushort_t* B = side ? B2 : B1;
        for (int kt = 0; kt < KP; kt += BK) {
            __syncthreads();  // protect LDS from prior iteration's readers
#pragma unroll
            for (int i = tid; i < BM * BK / 8; i += 512) {
                int r = i >> 3, c = i & 7;
                int gr = row0 + r;
                if (gr >= M) gr = M - 1;
                gload_lds16(A + (size_t)gr * KP + kt + c * 8, Alds + i * 8);
            }
#pragma unroll
            for (int i = tid; i < BN * BK / 8; i += 512) {
                int r = i >> 3, c = i & 7;
                gload_lds16(B + (size_t)r * KP + kt + c * 8, Blds + i * 8);
            }
            __syncthreads();
            bf16x8 a[2][M_REP], b[2][N_REP];
#pragma unroll
            for (int kk = 0; kk < 2; ++kk) {
#pragma unroll
                for (int m = 0; m < M_REP; ++m)
                    a[kk][m] = *(const bf16x8*)&Alds[(wm * WM + m * 16 + (lane & 15)) * BK + kk * 32 + (lane >> 4) * 8];
#pragma unroll
                for (int n = 0; n < N_REP; ++n)
                    b[kk][n] = *(const bf16x8*)&Blds[(wn * WN + n * 16 + (lane & 15)) * BK + kk * 32 + (lane >> 4) * 8];
            }
#pragma unroll
            for (int kk = 0; kk < 2; ++kk)
#pragma unroll
                for (int m = 0; m < M_REP; ++m)
#pragma unroll
                    for (int n = 0; n < N_REP; ++n)
                        acc[m][n] = __builtin_amdgcn_mfma_f32_16x16x32_bf16(a[kk][m], b[kk][n], acc[m][n], 0, 0, 0);
        }
    }
#pragma unroll
    for (int n = 0; n < N_REP; ++n) {
        int lcol = wn * WN + n * 16 + (lane & 15);
        float s = 0.f, q = 0.f;
#pragma unroll
        for (int m = 0; m < M_REP; ++m) {
#pragma unroll
            for (int r = 0; r < 4; ++r) {
                int row = row0 + wm * WM + m * 16 + (lane >> 4) * 4 + r;
                float v = acc[m][n][r];
                if (row < M) {
                    if (MODE == 0) {
                        out_bf[(size_t)row * 256 + lcol] = f2bf(v);
                        s += v;
                        q += v * v;
                    } else {
                        if (lcol < 64) {
                            out_bf[(size_t)row * 64 + lcol] = f2bf(v);
                        } else {
                            int c = lcol - 64;
                            float bv = (c < 47) ? bias[c] : 0.f;
                            out_f[(size_t)row * 64 + c] = v + bv;
                        }
                    }
                }
            }
        }
        if (MODE == 0) {
            s += __shfl_xor(s, 16); s += __shfl_xor(s, 32);
            q += __shfl_xor(q, 16); q += __shfl_xor(q, 32);
            if (lane < 16) {
                atomicAdd(&sstat[0][lcol], s);
                atomicAdd(&sstat[1][lcol], q);
            }
        }
    }
    if (MODE == 0) {
        __syncthreads();
        for (int i = tid; i < BN; i += 512) {
            atomicAdd(&stats[i], sstat[0][i]);
            atomicAdd(&stats[256 + i], sstat[1][i]);
        }
    }
}

// ---------- BN apply + ReLU, bf16 in / bf16 out ----------
__global__ void k_bnrelu(const ushort_t* __restrict__ h, const float* __restrict__ stats,
                         const float* __restrict__ g, const float* __restrict__ be,
                         int M, ushort_t* __restrict__ out) {
    int c = threadIdx.x;
    float invM = 1.f / (float)M;
    float mean = stats[c] * invM;
    float var = stats[256 + c] * invM - mean * mean;
    float sc = g[c] * rsqrtf(var + 1e-5f);
    float sh = be[c] - mean * sc;
    for (int r = blockIdx.x; r < M; r += gridDim.x) {
        float v = bf2f(h[(size_t)r * 256 + c]) * sc + sh;
        out[(size_t)r * 256 + c] = f2bf(fmaxf(v, 0.f));
    }
}

// ---------- layer 2: aggregate 64-dim transformed feats + log_softmax ----------
__global__ void k_agg_lsm(const ushort_t* __restrict__ t2, const float* __restrict__ r2,
                          const int* __restrict__ offs, const int* __restrict__ deg,
                          const int* __restrict__ csr, int N, float* __restrict__ out) {
    constexpr int BATCH = 16;
    int wid = (blockIdx.x * blockDim.x + threadIdx.x) >> 6;
    int lane = threadIdx.x & 63;
    if (wid >= N) return;
    int off = offs[wid], cnt = deg[wid];
    float acc = 0.f;
    const ushort_t* tp = t2 + lane;
    if (cnt > 0) {
        int idx[BATCH];
#pragma unroll
        for (int u = 0; u < BATCH; ++u) idx[u] = csr[off + min(u, cnt - 1)];
        for (int b = 0; b < cnt; b += BATCH) {
            ushort_t d[BATCH];
#pragma unroll
            for (int u = 0; u < BATCH; ++u) d[u] = tp[(size_t)idx[u] * 64];
            int nxt = b + BATCH;
#pragma unroll
            for (int u = 0; u < BATCH; ++u) idx[u] = csr[off + min(nxt + u, cnt - 1)];
#pragma unroll
            for (int u = 0; u < BATCH; ++u) {
                float w = (b + u < cnt) ? 1.f : 0.f;
                acc += w * bf2f(d[u]);
            }
        }
    }
    float v = acc / fmaxf((float)cnt, 1.f) + r2[(size_t)wid * 64 + lane];
    if (lane >= 47) v = -1e30f;
    float m = v;
    for (int o = 32; o > 0; o >>= 1) m = fmaxf(m, __shfl_xor(m, o));
    float e = (lane < 47) ? expf(v - m) : 0.f;
    float sum = e;
    for (int o = 32; o > 0; o >>= 1) sum += __shfl_xor(sum, o);
    if (lane < 47) out[(size_t)wid * 47 + lane] = v - m - logf(sum);
}

extern "C" void kernel_launch(void* const* d_in, const int* in_sizes, int n_in,
                              void* d_out, int out_size, void* d_ws, size_t ws_size,
                              hipStream_t stream) {
    const float* x   = (const float*)d_in[0];
    const int*   ei  = (const int*)d_in[1];
    const float* wl0 = (const float*)d_in[2];
    const float* wr0 = (const float*)d_in[3];
    const float* g0  = (const float*)d_in[5];
    const float* be0 = (const float*)d_in[6];
    const float* wl1 = (const float*)d_in[7];
    const float* wr1 = (const float*)d_in[8];
    const float* g1  = (const float*)d_in[10];
    const float* be1 = (const float*)d_in[11];
    const float* wl2 = (const float*)d_in[12];
    const float* wr2 = (const float*)d_in[13];
    const float* b2  = (const float*)d_in[14];
    float* out = (float*)d_out;

    const int N = in_sizes[0] / 100;
    const int E = in_sizes[1] / 2;
    const int* src = ei;
    const int* dst = ei + E;

    // workspace carve (256B aligned)
    char* p = (char*)d_ws;
    auto alloc = [&](size_t bytes) -> char* {
        char* r = p;
        p += (bytes + 255) & ~(size_t)255;
        return r;
    };
    ushort_t* xb   = (ushort_t*)alloc((size_t)N * 128 * 2);
    ushort_t* hbuf = (ushort_t*)alloc((size_t)N * 256 * 2);
    ushort_t* mean = (ushort_t*)alloc((size_t)N * 256 * 2);
    ushort_t* hpre = (ushort_t*)alloc((size_t)N * 256 * 2);
    int* deg  = (int*)alloc((size_t)N * 4);
    int* offs = (int*)alloc((size_t)N * 4);
    int* csr  = (int*)alloc((size_t)E * 4);
    int* ebin = (int*)alloc((size_t)E * 4);
    const int NBLK = 128;
    const int nbins = (N + 1023) >> 10;           // 98 for N=100000
    const int scanN = nbins * NBLK;
    int* binCnt = (int*)alloc((size_t)scanN * 4);
    int* binOff = (int*)alloc((size_t)scanN * 4);
    int* bsum = (int*)alloc(1024 * 4);
    float* stats = (float*)alloc(512 * 4);
    ushort_t* wlt0 = (ushort_t*)alloc(256 * 128 * 2);
    ushort_t* wrt0 = (ushort_t*)alloc(256 * 128 * 2);
    ushort_t* wlt1 = (ushort_t*)alloc(256 * 256 * 2);
    ushort_t* wrt1 = (ushort_t*)alloc(256 * 256 * 2);
    ushort_t* wcat2 = (ushort_t*)alloc(128 * 256 * 2);
    if ((size_t)(p - (char*)d_ws) > ws_size) return;  // insufficient scratch

    // layer-2 buffers alias `mean` (unused after layer-1 GEMM)
    ushort_t* t2 = mean;                               // [N][64] bf16
    float*    r2 = (float*)((char*)mean + (size_t)N * 64 * 2);  // [N][64] f32

    k_cast_x<<<2048, 256, 0, stream>>>(x, xb, N);
    k_cast_w<<<128, 256, 0, stream>>>(wl0, wlt0, 100, 256, 128, 256);
    k_cast_w<<<128, 256, 0, stream>>>(wr0, wrt0, 100, 256, 128, 256);
    k_cast_w<<<128, 256, 0, stream>>>(wl1, wlt1, 256, 256, 256, 256);
    k_cast_w<<<128, 256, 0, stream>>>(wr1, wrt1, 256, 256, 256, 256);
    k_cast_w<<<128, 256, 0, stream>>>(wl2, wcat2, 256, 47, 256, 64);
    k_cast_w<<<128, 256, 0, stream>>>(wr2, wcat2 + 64 * 256, 256, 47, 256, 64);

    // ---- CSR build (binned counting sort) ----
    const int CH = (E + NBLK - 1) / NBLK;
    k_bincount<<<NBLK, 256, 0, stream>>>(dst, E, CH, nbins, NBLK, binCnt);
    int NB2 = (scanN + 1023) / 1024;
    k_blocksum<<<NB2, 1024, 0, stream>>>(binCnt, scanN, bsum);
    k_scanb<<<1, 64, 0, stream>>>(bsum, NB2);
    k_exscan<<<NB2, 1024, 0, stream>>>(binCnt, bsum, scanN, binOff);
    k_binscatter<<<NBLK, 256, 0, stream>>>(src, dst, E, CH, nbins, NBLK, binOff, ebin);
    k_bincsr<<<nbins, 1024, 0, stream>>>(ebin, binOff, E, N, nbins, NBLK, offs, deg, csr);

    int aggBlocks = (N + 3) / 4;      // 4 waves (nodes) per 256-thread block
    int gemmM = (N + 127) / 128;

    // ---- layer 0 ----
    k_agg<128, 16><<<aggBlocks, 256, 0, stream>>>(xb, offs, deg, csr, N, mean);
    hipMemsetAsync(stats, 0, 512 * 4, stream);
    k_gemm<256, 2, 4, 0><<<gemmM, 512, 0, stream>>>(
        mean, wlt0, xb, wrt0, 128, nullptr, hpre, nullptr, stats, N);
    k_bnrelu<<<2048, 256, 0, stream>>>(hpre, stats, g0, be0, N, hbuf);

    // ---- layer 1 ----
    k_agg<256, 8><<<aggBlocks, 256, 0, stream>>>(hbuf, offs, deg, csr, N, mean);
    hipMemsetAsync(stats, 0, 512 * 4, stream);
    k_gemm<256, 2, 4, 0><<<gemmM, 512, 0, stream>>>(
        mean, wlt1, hbuf, wrt1, 256, nullptr, hpre, nullptr, stats, N);
    k_bnrelu<<<2048, 256, 0, stream>>>(hpre, stats, g1, be1, N, hbuf);

    // ---- layer 2 (transform-first: mean(h)@wl2 == mean(h@wl2)) ----
    k_gemm<128, 2, 4, 1><<<gemmM, 512, 0, stream>>>(
        hbuf, wcat2, nullptr, nullptr, 256, b2, t2, r2, nullptr, N);
    k_agg_lsm<<<(N + 3) / 4, 256, 0, stream>>>(t2, r2, offs, deg, csr, N, out);
}